// Round 1
// baseline (599.251 us; speedup 1.0000x reference)
//
#include <hip/hip_runtime.h>
#include <math.h>

typedef unsigned short u16;
typedef __attribute__((ext_vector_type(8))) short bf16x8;
typedef __attribute__((ext_vector_type(8))) unsigned short u16x8;
typedef __attribute__((ext_vector_type(4))) float f32x4;

__device__ __forceinline__ u16 f2bf(float f){
  union { float f; unsigned u; } c; c.f = f;
  unsigned u = c.u;
  return (u16)((u + 0x7fffu + ((u >> 16) & 1u)) >> 16);
}
__device__ __forceinline__ float bf2f(u16 h){
  union { unsigned u; float f; } c; c.u = ((unsigned)h) << 16;
  return c.f;
}
__device__ __forceinline__ void gload_lds16(const void* g, void* l){
  __builtin_amdgcn_global_load_lds((const __attribute__((address_space(1))) void*)g,
                                   (__attribute__((address_space(3))) void*)l, 16, 0, 0);
}
// XOR swizzle within a 1024B LDS row: spreads 16B chunks across banks
__device__ __forceinline__ int swz(int row, int bc){
  return (row << 10) + (bc ^ ((row & 7) << 4));
}

// ---------------- weight transpose + f32->bf16 : in [K][N] f32 -> out [N][K] bf16
__global__ void transpose_cvt(const float* __restrict__ in, u16* __restrict__ out, int K, int N){
  __shared__ float tile[32][33];
  int n0 = blockIdx.x << 5, k0 = blockIdx.y << 5;
  int tx = threadIdx.x, ty = threadIdx.y;
  #pragma unroll
  for (int r = 0; r < 32; r += 8)
    tile[ty + r][tx] = in[(size_t)(k0 + ty + r) * N + n0 + tx];
  __syncthreads();
  #pragma unroll
  for (int r = 0; r < 32; r += 8)
    out[(size_t)(n0 + ty + r) * K + k0 + tx] = f2bf(tile[tx][ty + r]);
}

// ---------------- layernorm: f32 [rows][1024] -> bf16 [rows][1024]
__device__ __forceinline__ float blockReduce(float v, float* ws){
  #pragma unroll
  for (int m = 1; m < 64; m <<= 1) v += __shfl_xor(v, m, 64);
  int w = threadIdx.x >> 6;
  __syncthreads();
  if ((threadIdx.x & 63) == 0) ws[w] = v;
  __syncthreads();
  return ws[0] + ws[1] + ws[2] + ws[3];
}

struct U16x4 { u16 x, y, z, w; };

__global__ __launch_bounds__(256) void ln_kernel(const float* __restrict__ in, const float* __restrict__ g,
    const float* __restrict__ be, u16* __restrict__ out){
  __shared__ float ws[4];
  int row = blockIdx.x;
  const float4 v = ((const float4*)(in + ((size_t)row << 10)))[threadIdx.x];
  float s = v.x + v.y + v.z + v.w;
  s = blockReduce(s, ws);
  float mean = s * (1.f / 1024.f);
  float dx = v.x - mean, dy = v.y - mean, dz = v.z - mean, dw = v.w - mean;
  float s2 = dx*dx + dy*dy + dz*dz + dw*dw;
  s2 = blockReduce(s2, ws);
  float rstd = rsqrtf(s2 * (1.f / 1024.f) + 1e-5f);
  float4 gv = ((const float4*)g)[threadIdx.x];
  float4 bv = ((const float4*)be)[threadIdx.x];
  U16x4 ov;
  ov.x = f2bf(dx * rstd * gv.x + bv.x);
  ov.y = f2bf(dy * rstd * gv.y + bv.y);
  ov.z = f2bf(dz * rstd * gv.z + bv.z);
  ov.w = f2bf(dw * rstd * gv.w + bv.w);
  ((U16x4*)(out + ((size_t)row << 10)))[threadIdx.x] = ov;
}

// ---------------- generic bf16 GEMM: A [M][K], Bt [N][K], 128x128 tile, BK=32
// EPI 0: out bf16 scatter to [B*NH, S, HD] (+bias)      (QKV)
// EPI 1: out f32 = acc + bias + add                     (proj+res / ffn2+res)
// EPI 2: out bf16 = gelu(acc + bias)                    (ffn1)
template<int EPI>
__global__ __launch_bounds__(256) void gemm_kernel(
    const u16* __restrict__ A, const u16* __restrict__ Bt,
    const float* __restrict__ bias, const float* __restrict__ add,
    void* __restrict__ out, int M, int N, int K)
{
  __shared__ u16 As[128 * 32];
  __shared__ u16 Bs[128 * 32];
  const int tid = threadIdx.x;
  const int wave = tid >> 6, lane = tid & 63;
  const int nbx = N >> 7;
  const int bx = blockIdx.x % nbx, by = blockIdx.x / nbx;
  const int m0 = by << 7, n0 = bx << 7;
  const int lcol = lane & 15, lrow4 = lane >> 4;
  const int wr = wave >> 1, wc = wave & 1;

  f32x4 acc[4][4] = {};

  const int srow = wave * 32 + (lane >> 2);
  const int scol = (lane & 3) * 16;
  const u16* Abase = A + (size_t)(m0 + srow) * K;
  const u16* Bbase = Bt + (size_t)(n0 + srow) * K;

  for (int kt = 0; kt < K; kt += 32) {
    #pragma unroll
    for (int is = 0; is < 2; ++is) {
      gload_lds16((const char*)(Abase + (size_t)is * 16 * K + kt) + scol, (void*)&As[(wave*32 + is*16) * 32]);
      gload_lds16((const char*)(Bbase + (size_t)is * 16 * K + kt) + scol, (void*)&Bs[(wave*32 + is*16) * 32]);
    }
    __syncthreads();
    bf16x8 af[4], bfr[4];
    #pragma unroll
    for (int i = 0; i < 4; ++i) {
      af[i]  = *(const bf16x8*)&As[(wr*64 + i*16 + lcol) * 32 + lrow4 * 8];
      bfr[i] = *(const bf16x8*)&Bs[(wc*64 + i*16 + lcol) * 32 + lrow4 * 8];
    }
    #pragma unroll
    for (int i = 0; i < 4; ++i)
      #pragma unroll
      for (int j = 0; j < 4; ++j)
        acc[i][j] = __builtin_amdgcn_mfma_f32_16x16x32_bf16(af[i], bfr[j], acc[i][j], 0, 0, 0);
    __syncthreads();
  }

  #pragma unroll
  for (int i = 0; i < 4; ++i) {
    const int gmb = m0 + wr*64 + i*16 + lrow4*4;
    #pragma unroll
    for (int j = 0; j < 4; ++j) {
      const int gn = n0 + wc*64 + j*16 + lcol;
      const float bs = bias[gn];
      #pragma unroll
      for (int r = 0; r < 4; ++r) {
        const int gm = gmb + r;
        float v = acc[i][j][r] + bs;
        if constexpr (EPI == 0) {
          int b = gm >> 11, s = gm & 2047;
          int h = gn >> 6, d = gn & 63;
          ((u16*)out)[((((size_t)((b << 4) + h) << 11) + s) << 6) + d] = f2bf(v);
        } else if constexpr (EPI == 1) {
          ((float*)out)[(size_t)gm * N + gn] = v + add[(size_t)gm * N + gn];
        } else {
          ((u16*)out)[(size_t)gm * N + gn] = f2bf(0.5f * v * (1.f + erff(v * 0.70710678118f)));
        }
      }
    }
  }
}

// ---------------- windowed attention
// Each block: one (window, bh). Q,K read from global; V transposed to LDS; P via LDS.
// phase 0: even windows (disjoint spans) store wgt*wo; phase 1: odd windows add (store for p>=1920).
template<int NJ>  // NJ = W/16 (24 or 32)
__device__ void attn_core(const u16* __restrict__ Qp, const u16* __restrict__ Kp,
    u16* __restrict__ ctx, char* vtb, char* plb,
    int start, int widx, int phase, int bh)
{
  const int tid = threadIdx.x, wave = tid >> 6, lane = tid & 63;
  const int lcol = lane & 15, lrow4 = lane >> 4;
  const float scale = 0.125f;  // 64^-0.5
  const int b = bh >> 4, h = bh & 15;

  for (int qt = wave; qt < NJ; qt += 4) {
    const int q0 = qt * 16;
    const bf16x8 aq0 = *(const bf16x8*)(Qp + (q0 + lcol) * 64 + lrow4 * 8);
    const bf16x8 aq1 = *(const bf16x8*)(Qp + (q0 + lcol) * 64 + 32 + lrow4 * 8);
    f32x4 acc[NJ] = {};
    #pragma unroll
    for (int j = 0; j < NJ; ++j) {
      bf16x8 k0 = *(const bf16x8*)(Kp + (j*16 + lcol) * 64 + lrow4 * 8);
      bf16x8 k1 = *(const bf16x8*)(Kp + (j*16 + lcol) * 64 + 32 + lrow4 * 8);
      acc[j] = __builtin_amdgcn_mfma_f32_16x16x32_bf16(aq0, k0, acc[j], 0, 0, 0);
      acc[j] = __builtin_amdgcn_mfma_f32_16x16x32_bf16(aq1, k1, acc[j], 0, 0, 0);
    }
    // softmax: row = (lane>>4)*4 + r, cols spread over 16 lanes x NJ frags
    float rs[4];
    #pragma unroll
    for (int r = 0; r < 4; ++r) {
      float mx = -3.0e38f;
      #pragma unroll
      for (int j = 0; j < NJ; ++j) mx = fmaxf(mx, acc[j][r]);
      mx = fmaxf(mx, __shfl_xor(mx, 1, 64));
      mx = fmaxf(mx, __shfl_xor(mx, 2, 64));
      mx = fmaxf(mx, __shfl_xor(mx, 4, 64));
      mx = fmaxf(mx, __shfl_xor(mx, 8, 64));
      float sum = 0.f;
      const int prow = wave * 16 + lrow4 * 4 + r;
      #pragma unroll
      for (int j = 0; j < NJ; ++j) {
        float e = __expf((acc[j][r] - mx) * scale);
        sum += e;
        *(u16*)(plb + swz(prow, (j*16 + lcol) * 2)) = f2bf(e);
      }
      sum += __shfl_xor(sum, 1, 64);
      sum += __shfl_xor(sum, 2, 64);
      sum += __shfl_xor(sum, 4, 64);
      sum += __shfl_xor(sum, 8, 64);
      rs[r] = 1.f / sum;  // folded into epilogue (same row<->lane mapping)
    }
    // PV: A = P (row = q), B = Vt (col = d)
    f32x4 o[4] = {};
    #pragma unroll
    for (int kk = 0; kk < NJ / 2; ++kk) {
      bf16x8 pa = *(const bf16x8*)(plb + swz(wave*16 + lcol, (kk*32 + lrow4*8) * 2));
      #pragma unroll
      for (int d = 0; d < 4; ++d) {
        bf16x8 pb = *(const bf16x8*)(vtb + swz(d*16 + lcol, (kk*32 + lrow4*8) * 2));
        o[d] = __builtin_amdgcn_mfma_f32_16x16x32_bf16(pa, pb, o[d], 0, 0, 0);
      }
    }
    // epilogue: blend weight + scatter to ctx [B,S,HID]
    #pragma unroll
    for (int r = 0; r < 4; ++r) {
      int p = start + q0 + lrow4 * 4 + r;
      int rel = p - (widx * 256 - 128);
      float wgt = (rel < 256) ? ((widx == 0) ? 1.f : (float)rel * (1.f / 255.f))
                              : ((widx == 7) ? 1.f : (1.f - (float)(rel - 256) * (1.f / 255.f)));
      float rw = rs[r] * wgt;
      size_t base = (((size_t)(b << 11) + (size_t)p) << 10) + (h << 6);
      #pragma unroll
      for (int d = 0; d < 4; ++d) {
        size_t idx = base + d * 16 + lcol;
        float val = o[d][r] * rw;
        if (phase == 0)        ctx[idx] = f2bf(val);
        else if (p >= 1920)    ctx[idx] = f2bf(val);
        else                   ctx[idx] = f2bf(bf2f(ctx[idx]) + val);
      }
    }
  }
}

__global__ __launch_bounds__(256, 1) void attn_kernel(const u16* __restrict__ qg, const u16* __restrict__ kg,
    const u16* __restrict__ vg, u16* __restrict__ ctx, int phase){
  __shared__ u16 Vt[64 * 512];
  __shared__ u16 Pl[64 * 512];
  int widx = (((int)blockIdx.x >> 6) << 1) + phase;
  int bh = blockIdx.x & 63;
  int i0 = widx << 8;
  int start = i0 - 128; if (start < 0) start = 0;
  int end = i0 + 384;   if (end > 2048) end = 2048;
  int W = end - start;
  const u16* Qp = qg + (((size_t)bh << 11) + start) * 64;
  const u16* Kp = kg + (((size_t)bh << 11) + start) * 64;
  const u16* Vp = vg + (((size_t)bh << 11) + start) * 64;
  char* vtb = (char*)Vt;
  char* plb = (char*)Pl;
  // stage V transposed (swizzled) into LDS
  for (int c = threadIdx.x; c < W * 8; c += 256) {
    int key = c >> 3, d0 = (c & 7) << 3;
    u16x8 vv = *(const u16x8*)(Vp + key * 64 + d0);
    #pragma unroll
    for (int z = 0; z < 8; ++z)
      *(u16*)(vtb + swz(d0 + z, key * 2)) = vv[z];
  }
  __syncthreads();
  if (W == 512) attn_core<32>(Qp, Kp, ctx, vtb, plb, start, widx, phase, bh);
  else          attn_core<24>(Qp, Kp, ctx, vtb, plb, start, widx, phase, bh);
}

// ---------------- host
extern "C" void kernel_launch(void* const* d_in, const int* in_sizes, int n_in,
                              void* d_out, int out_size, void* d_ws, size_t ws_size,
                              hipStream_t stream) {
  const float* hidden = (const float*)d_in[0];
  const float* ln1_g  = (const float*)d_in[1];
  const float* ln1_b  = (const float*)d_in[2];
  const float* wq     = (const float*)d_in[3];
  const float* bq     = (const float*)d_in[4];
  const float* wk     = (const float*)d_in[5];
  const float* bk     = (const float*)d_in[6];
  const float* wv     = (const float*)d_in[7];
  const float* bv     = (const float*)d_in[8];
  const float* wproj  = (const float*)d_in[9];
  const float* bproj  = (const float*)d_in[10];
  const float* ln2_g  = (const float*)d_in[11];
  const float* ln2_b  = (const float*)d_in[12];
  const float* w1     = (const float*)d_in[13];
  const float* b1     = (const float*)d_in[14];
  const float* w2     = (const float*)d_in[15];
  const float* b2     = (const float*)d_in[16];

  char* ws = (char*)d_ws;
  u16* xb   = (u16*)(ws + 0);           // 16 MiB  (LN1 out; reused as LN2 out)
  u16* wqT  = (u16*)(ws + 16777216);
  u16* wkT  = (u16*)(ws + 18874368);
  u16* wvT  = (u16*)(ws + 20971520);
  u16* wpT  = (u16*)(ws + 23068672);
  u16* w1T  = (u16*)(ws + 25165824);    // 8 MiB
  u16* w2T  = (u16*)(ws + 33554432);    // 8 MiB
  u16* qb   = (u16*)(ws + 41943040);    // 16 MiB
  u16* kb   = (u16*)(ws + 58720256);    // 16 MiB
  u16* vb   = (u16*)(ws + 75497472);    // 16 MiB
  u16* ctx  = (u16*)(ws + 92274688);    // 16 MiB
  float* res2 = (float*)(ws + 109051904); // 32 MiB
  u16* mid  = (u16*)(ws + 41943040);    // 64 MiB, reuses qb..ctx

  dim3 tb(32, 8);
  transpose_cvt<<<dim3(32, 32), tb, 0, stream>>>(wq, wqT, 1024, 1024);
  transpose_cvt<<<dim3(32, 32), tb, 0, stream>>>(wk, wkT, 1024, 1024);
  transpose_cvt<<<dim3(32, 32), tb, 0, stream>>>(wv, wvT, 1024, 1024);
  transpose_cvt<<<dim3(32, 32), tb, 0, stream>>>(wproj, wpT, 1024, 1024);
  transpose_cvt<<<dim3(128, 32), tb, 0, stream>>>(w1, w1T, 1024, 4096);
  transpose_cvt<<<dim3(32, 128), tb, 0, stream>>>(w2, w2T, 4096, 1024);

  ln_kernel<<<8192, 256, 0, stream>>>(hidden, ln1_g, ln1_b, xb);

  gemm_kernel<0><<<512, 256, 0, stream>>>(xb, wqT, bq, nullptr, qb, 8192, 1024, 1024);
  gemm_kernel<0><<<512, 256, 0, stream>>>(xb, wkT, bk, nullptr, kb, 8192, 1024, 1024);
  gemm_kernel<0><<<512, 256, 0, stream>>>(xb, wvT, bv, nullptr, vb, 8192, 1024, 1024);

  attn_kernel<<<256, 256, 0, stream>>>(qb, kb, vb, ctx, 0);
  attn_kernel<<<256, 256, 0, stream>>>(qb, kb, vb, ctx, 1);

  gemm_kernel<1><<<512, 256, 0, stream>>>(ctx, wpT, bproj, hidden, res2, 8192, 1024, 1024);

  ln_kernel<<<8192, 256, 0, stream>>>(res2, ln2_g, ln2_b, xb);

  gemm_kernel<2><<<2048, 256, 0, stream>>>(xb, w1T, b1, nullptr, mid, 8192, 4096, 1024);
  gemm_kernel<1><<<512, 256, 0, stream>>>(mid, w2T, b2, res2, (float*)d_out, 8192, 1024, 4096);
}